// Round 8
// baseline (254.769 us; speedup 1.0000x reference)
//
#include <hip/hip_runtime.h>
#include <hip/hip_bf16.h>

#define NPTS 131072
#define KCL  1024
#define DD   256

typedef __bf16 bf16x8 __attribute__((ext_vector_type(8)));
typedef __bf16 bf16x4 __attribute__((ext_vector_type(4)));
typedef float  f32x4  __attribute__((ext_vector_type(4)));

#define GLOAD_LDS16(gsrc, ldst)                                                             \
    __builtin_amdgcn_global_load_lds(                                                       \
        (const __attribute__((address_space(1))) unsigned int*)(gsrc),                      \
        (__attribute__((address_space(3))) unsigned int*)(ldst), 16, 0, 0)

// out layout: [0] = mean, [1 .. K*D] = bins, [1+K*D .. 1+K*D+K) = nums
__global__ __launch_bounds__(256) void init_out_kernel(const float* __restrict__ bins_in,
                                                       const float* __restrict__ nums_in,
                                                       float* __restrict__ out,
                                                       int* __restrict__ counts) {
    int i = blockIdx.x * 256 + threadIdx.x;
    if (i == 0) out[0] = 0.0f;
    if (i < KCL * DD) out[1 + i] = bins_in[i];
    if (i < KCL) { out[1 + KCL * DD + i] = nums_in[i]; counts[i] = 0; }
}

// one wave per codebook row: convert to bf16 in PERMUTED tile layout + fp32 c_sq.
// Permuted layout: element (cluster c, dim d) with tile=c>>4, cl=c&15,
// t=d>>5, lg=(d>>3)&3, j=d&7  ->  cbh[tile*4096 + t*512 + lg*128 + cl*8 + j]
// so a wave's B-frag read t is 64 consecutive 16B chunks: (t*64+lane)*16 bytes.
__global__ __launch_bounds__(256) void prep_cb_kernel(const float* __restrict__ cb,
                                                      __bf16* __restrict__ cbh,
                                                      float* __restrict__ csq) {
    int gid  = blockIdx.x * 256 + threadIdx.x;
    int row  = gid >> 6;
    int lane = threadIdx.x & 63;
    float4 v = *reinterpret_cast<const float4*>(cb + (size_t)row * DD + lane * 4);
    bf16x4 h;
    h[0] = (__bf16)v.x; h[1] = (__bf16)v.y; h[2] = (__bf16)v.z; h[3] = (__bf16)v.w;
    int d0 = lane * 4;
    size_t off = (size_t)(row >> 4) * 4096 + (size_t)(d0 >> 5) * 512
               + (size_t)((d0 >> 3) & 3) * 128 + (size_t)(row & 15) * 8 + (d0 & 7);
    *reinterpret_cast<bf16x4*>(cbh + off) = h;
    float ss = v.x * v.x + v.y * v.y + v.z * v.z + v.w * v.w;
#pragma unroll
    for (int m = 1; m < 64; m <<= 1) ss += __shfl_xor(ss, m, 64);
    if (lane == 0) csq[row] = ss;
}

// main: 4 waves/block, each wave owns 64 points (4 row-tiles); all 1024 clusters.
// 16 KB groups (2 K-tiles) per sync; ring of 3 buffers; prefetch depth 2 with
// counted vmcnt(4) + raw s_barrier; 4 MFMA chains; setprio around MFMAs.
__global__ __launch_bounds__(256) void kmeans_kernel(const float* __restrict__ x,
                                                     const __bf16* __restrict__ cbp,
                                                     const float* __restrict__ csq,
                                                     unsigned short* __restrict__ bucketg,
                                                     int* __restrict__ counts,
                                                     float* __restrict__ out) {
    __shared__ __bf16 sh[3 * 8192];   // 3 buffers x 16 KB = 48 KB
    __shared__ float  css[KCL];       // 4 KB
    __shared__ int bucket_s[256];
    const int tid  = threadIdx.x;
    const int lane = tid & 63;
    const int wid  = tid >> 6;
    const int l15  = lane & 15;
    const int lg   = lane >> 4;
    const int rowbase = blockIdx.x * 256 + wid * 64;

    // ---- load x tile (64 rows) as bf16 a-frags in regs, fp32 x_sq on the fly ----
    bf16x8 A[4][8];
    float xsq_e[4][4];
#pragma unroll
    for (int rt = 0; rt < 4; ++rt) {
        const float* xr = x + (size_t)(rowbase + rt * 16 + l15) * DD + lg * 8;
        float ss = 0.0f;
#pragma unroll
        for (int t = 0; t < 8; ++t) {
            float4 lo = *reinterpret_cast<const float4*>(xr + t * 32);
            float4 hi = *reinterpret_cast<const float4*>(xr + t * 32 + 4);
            ss += lo.x * lo.x + lo.y * lo.y + lo.z * lo.z + lo.w * lo.w;
            ss += hi.x * hi.x + hi.y * hi.y + hi.z * hi.z + hi.w * hi.w;
            bf16x8 a;
            a[0] = (__bf16)lo.x; a[1] = (__bf16)lo.y; a[2] = (__bf16)lo.z; a[3] = (__bf16)lo.w;
            a[4] = (__bf16)hi.x; a[5] = (__bf16)hi.y; a[6] = (__bf16)hi.z; a[7] = (__bf16)hi.w;
            A[rt][t] = a;
        }
        ss += __shfl_xor(ss, 16, 64);
        ss += __shfl_xor(ss, 32, 64);
#pragma unroll
        for (int r = 0; r < 4; ++r) xsq_e[rt][r] = __shfl(ss, lg * 4 + r, 64);
    }

    // stage csq into LDS (1024 floats by 256 threads)
    {
        float4 c4 = *reinterpret_cast<const float4*>(csq + tid * 4);
        *reinterpret_cast<float4*>(css + tid * 4) = c4;
    }

    // packed argmin: low 10 mantissa bits of d2 carry the cluster index
    float minp[4][4];
    float ssum0 = 0.0f, ssum1 = 0.0f;
#pragma unroll
    for (int rt = 0; rt < 4; ++rt)
#pragma unroll
        for (int r = 0; r < 4; ++r) minp[rt][r] = 3.4e38f;

    const char* cbB = (const char*)cbp;
    char* shB = (char*)sh;

    // stage one 16 KB group: 256 threads x 16 B x 4
    auto stage = [&](int G, int buf) {
        const char* src = cbB + (size_t)G * 16384 + tid * 16;
        char* dst = shB + buf * 16384 + tid * 16;
        GLOAD_LDS16(src, dst);
        GLOAD_LDS16(src + 4096, dst + 4096);
        GLOAD_LDS16(src + 8192, dst + 8192);
        GLOAD_LDS16(src + 12288, dst + 12288);
    };

    auto compute_subtile = [&](const __bf16* tb, int kt, float cs) {
        bf16x8 B[8];
#pragma unroll
        for (int t = 0; t < 8; ++t)
            B[t] = *reinterpret_cast<const bf16x8*>(tb + (t * 64 + lane) * 8);
        f32x4 acc[4];
#pragma unroll
        for (int rt = 0; rt < 4; ++rt) acc[rt] = (f32x4){0.f, 0.f, 0.f, 0.f};
        __builtin_amdgcn_s_setprio(1);
#pragma unroll
        for (int t = 0; t < 8; ++t) {
#pragma unroll
            for (int rt = 0; rt < 4; ++rt)
                acc[rt] = __builtin_amdgcn_mfma_f32_16x16x32_bf16(A[rt][t], B[t], acc[rt], 0, 0, 0);
        }
        __builtin_amdgcn_s_setprio(0);
        const unsigned colb = (unsigned)(kt * 16 + l15);
#pragma unroll
        for (int rt = 0; rt < 4; ++rt) {
#pragma unroll
            for (int r = 0; r < 4; ++r) {
                float d2 = fmaf(-2.0f, acc[rt][r], xsq_e[rt][r] + cs);
                if (rt & 1) ssum1 += __builtin_amdgcn_sqrtf(d2);
                else        ssum0 += __builtin_amdgcn_sqrtf(d2);
                float p = __uint_as_float((__float_as_uint(d2) & 0xFFFFFC00u) | colb);
                minp[rt][r] = fminf(minp[rt][r], p);
            }
        }
    };

    // drain prologue (x loads consumed, css/LDS written), sync baseline
    __syncthreads();

    // prologue staging: groups 0,1 into buffers 0,1
    stage(0, 0);
    stage(1, 1);
    asm volatile("s_waitcnt vmcnt(4)" ::: "memory");   // group 0 landed
    __builtin_amdgcn_s_barrier();

#define KM_BODY(G, BG, BS)                                                    \
    {                                                                         \
        stage((G) + 2, (BS));                                                 \
        float cs0 = css[(G) * 32 + l15];                                      \
        float cs1 = css[(G) * 32 + 16 + l15];                                 \
        compute_subtile(sh + (BG) * 8192, (G) * 2, cs0);                      \
        compute_subtile(sh + (BG) * 8192 + 4096, (G) * 2 + 1, cs1);           \
        asm volatile("s_waitcnt vmcnt(4)" ::: "memory");                      \
        __builtin_amdgcn_s_barrier();                                         \
    }

    for (int G = 0; G < 30; G += 3) {
        KM_BODY(G, 0, 2)
        KM_BODY(G + 1, 1, 0)
        KM_BODY(G + 2, 2, 1)
    }
    // tail: group 30 (buf 0), group 31 (buf 1)
    {
        float cs0 = css[30 * 32 + l15];
        float cs1 = css[30 * 32 + 16 + l15];
        compute_subtile(sh + 0 * 8192, 60, cs0);
        compute_subtile(sh + 0 * 8192 + 4096, 61, cs1);
        asm volatile("s_waitcnt vmcnt(0)" ::: "memory");
        __builtin_amdgcn_s_barrier();
        float cs2 = css[31 * 32 + l15];
        float cs3 = css[31 * 32 + 16 + l15];
        compute_subtile(sh + 1 * 8192, 62, cs2);
        compute_subtile(sh + 1 * 8192 + 4096, 63, cs3);
    }
#undef KM_BODY

    // ---- per-row argmin across the 16 lanes of each group: pure fmin reduce ----
#pragma unroll
    for (int rt = 0; rt < 4; ++rt)
#pragma unroll
        for (int r = 0; r < 4; ++r) {
            float v = minp[rt][r];
#pragma unroll
            for (int m = 1; m <= 8; m <<= 1) v = fminf(v, __shfl_xor(v, m, 64));
            if (l15 == 0) bucket_s[wid * 64 + rt * 16 + lg * 4 + r] = (int)(__float_as_uint(v) & 1023u);
        }
    __syncthreads();

    {
        int b = bucket_s[tid];
        bucketg[blockIdx.x * 256 + tid] = (unsigned short)b;
        atomicAdd(&counts[b], 1);
    }

    // ---- mean partial ----
    float ssum = ssum0 + ssum1;
#pragma unroll
    for (int m = 1; m < 64; m <<= 1) ssum += __shfl_xor(ssum, m, 64);
    if (lane == 0) atomicAdd(out, ssum * 7.4505805969238281e-9f);  // 1/2^27 exact
}

// single-block Hillis-Steele exclusive scan of the 1024 cluster counts
__global__ __launch_bounds__(1024) void scan_kernel(const int* __restrict__ counts,
                                                    int* __restrict__ offs,
                                                    int* __restrict__ cursor) {
    __shared__ int tmp[1024];
    const int t = threadIdx.x;
    const int v = counts[t];
    tmp[t] = v;
    __syncthreads();
    for (int d = 1; d < 1024; d <<= 1) {
        int a = (t >= d) ? tmp[t - d] : 0;
        __syncthreads();
        tmp[t] += a;
        __syncthreads();
    }
    const int excl = tmp[t] - v;
    offs[t] = excl;
    cursor[t] = excl;
    if (t == 1023) offs[1024] = tmp[t];
}

// place point indices into cluster-sorted order; also record cluster per position
__global__ __launch_bounds__(256) void scatter_kernel(const unsigned short* __restrict__ bucket,
                                                      int* __restrict__ cursor,
                                                      int* __restrict__ sorted,
                                                      unsigned short* __restrict__ clpos) {
    int i = blockIdx.x * 256 + threadIdx.x;
    int b = bucket[i];
    int pos = atomicAdd(&cursor[b], 1);
    sorted[pos] = i;
    clpos[pos] = (unsigned short)b;
}

// point-parallel segmented reduction over cluster-sorted order.
__global__ __launch_bounds__(256) void gather_kernel(const float* __restrict__ x,
                                                     const int* __restrict__ sorted,
                                                     const unsigned short* __restrict__ clpos,
                                                     float* __restrict__ out) {
    const int lane = threadIdx.x & 63;
    const int wv   = blockIdx.x * 4 + (threadIdx.x >> 6);
    const int pbeg = wv * 128;
    float* bins = out + 1;
    float* nums = out + 1 + KCL * DD;

    float4 acc = {0.f, 0.f, 0.f, 0.f};
    int cur = clpos[pbeg];
    int seglen = 0;

    auto flush = [&](int nextc) {
        float* bp = bins + (size_t)cur * DD + lane * 4;
        atomicAdd(bp + 0, acc.x);
        atomicAdd(bp + 1, acc.y);
        atomicAdd(bp + 2, acc.z);
        atomicAdd(bp + 3, acc.w);
        if (lane == 0) atomicAdd(nums + cur, (float)seglen);
        acc.x = 0.f; acc.y = 0.f; acc.z = 0.f; acc.w = 0.f;
        seglen = 0;
        cur = nextc;
    };

    int rowA[8], rowB[8];
    int clsA[8], clsB[8];
#pragma unroll
    for (int i = 0; i < 8; ++i) { rowA[i] = sorted[pbeg + i]; clsA[i] = clpos[pbeg + i]; }

    for (int g = 0; g < 128; g += 16) {
#pragma unroll
        for (int i = 0; i < 8; ++i) {
            rowB[i] = sorted[pbeg + g + 8 + i];
            clsB[i] = clpos[pbeg + g + 8 + i];
        }
        {
            float4 v[8];
#pragma unroll
            for (int i = 0; i < 8; ++i)
                v[i] = *reinterpret_cast<const float4*>(x + (size_t)rowA[i] * DD + lane * 4);
#pragma unroll
            for (int i = 0; i < 8; ++i) {
                if (clsA[i] != cur) flush(clsA[i]);
                acc.x += v[i].x; acc.y += v[i].y; acc.z += v[i].z; acc.w += v[i].w;
                ++seglen;
            }
        }
        if (g + 16 < 128) {
#pragma unroll
            for (int i = 0; i < 8; ++i) {
                rowA[i] = sorted[pbeg + g + 16 + i];
                clsA[i] = clpos[pbeg + g + 16 + i];
            }
        }
        {
            float4 v[8];
#pragma unroll
            for (int i = 0; i < 8; ++i)
                v[i] = *reinterpret_cast<const float4*>(x + (size_t)rowB[i] * DD + lane * 4);
#pragma unroll
            for (int i = 0; i < 8; ++i) {
                if (clsB[i] != cur) flush(clsB[i]);
                acc.x += v[i].x; acc.y += v[i].y; acc.z += v[i].z; acc.w += v[i].w;
                ++seglen;
            }
        }
    }
    flush(0);
}

extern "C" void kernel_launch(void* const* d_in, const int* in_sizes, int n_in,
                              void* d_out, int out_size, void* d_ws, size_t ws_size,
                              hipStream_t stream) {
    const float* x    = (const float*)d_in[0];
    const float* cb   = (const float*)d_in[1];
    const float* bins = (const float*)d_in[2];
    const float* nums = (const float*)d_in[3];
    float* out = (float*)d_out;

    char* ws = (char*)d_ws;
    __bf16*         cbp    = (__bf16*)ws;                        // 512 KB permuted (dead after kmeans)
    float*          csq    = (float*)(ws + 512 * 1024);          // 4 KB
    unsigned short* bucket = (unsigned short*)(ws + 516 * 1024); // 256 KB
    int*            counts = (int*)(ws + 772 * 1024);            // 4 KB
    int*            offs   = (int*)(ws + 776 * 1024);            // 4 KB + 4
    int*            cursor = (int*)(ws + 781 * 1024);            // 4 KB
    unsigned short* clpos  = (unsigned short*)(ws + 785 * 1024); // 256 KB
    int*            sorted = (int*)cbp;                           // aliases cbp, 512 KB

    init_out_kernel<<<(1 + KCL * DD + KCL + 255) / 256, 256, 0, stream>>>(bins, nums, out, counts);
    prep_cb_kernel<<<KCL / 4, 256, 0, stream>>>(cb, cbp, csq);
    kmeans_kernel<<<NPTS / 256, 256, 0, stream>>>(x, cbp, csq, bucket, counts, out);
    scan_kernel<<<1, 1024, 0, stream>>>(counts, offs, cursor);
    scatter_kernel<<<NPTS / 256, 256, 0, stream>>>(bucket, cursor, sorted, clpos);
    gather_kernel<<<NPTS / 512, 256, 0, stream>>>(x, sorted, clpos, out);
}

// Round 9
// 247.188 us; speedup vs baseline: 1.0307x; 1.0307x over previous
//
#include <hip/hip_runtime.h>
#include <hip/hip_bf16.h>

#define NPTS 131072
#define KCL  1024
#define DD   256

typedef __bf16 bf16x8 __attribute__((ext_vector_type(8)));
typedef __bf16 bf16x4 __attribute__((ext_vector_type(4)));
typedef float  f32x4  __attribute__((ext_vector_type(4)));

#define GLOAD_LDS16(gsrc, ldst)                                                             \
    __builtin_amdgcn_global_load_lds(                                                       \
        (const __attribute__((address_space(1))) unsigned int*)(gsrc),                      \
        (__attribute__((address_space(3))) unsigned int*)(ldst), 16, 0, 0)

// out layout: [0] = mean, [1 .. K*D] = bins, [1+K*D .. 1+K*D+K) = nums
__global__ __launch_bounds__(256) void init_out_kernel(const float* __restrict__ bins_in,
                                                       const float* __restrict__ nums_in,
                                                       float* __restrict__ out,
                                                       int* __restrict__ counts) {
    int i = blockIdx.x * 256 + threadIdx.x;
    if (i == 0) out[0] = 0.0f;
    if (i < KCL * DD) out[1 + i] = bins_in[i];
    if (i < KCL) { out[1 + KCL * DD + i] = nums_in[i]; counts[i] = 0; }
}

// one wave per codebook row: convert to bf16 in PERMUTED tile layout + fp32 c_sq.
// Permuted layout: element (cluster c, dim d) with tile=c>>4, cl=c&15,
// t=d>>5, lg=(d>>3)&3, j=d&7  ->  cbh[tile*4096 + t*512 + lg*128 + cl*8 + j]
// so a wave's B-frag read t is 64 consecutive 16B chunks: (t*64+lane)*16 bytes.
__global__ __launch_bounds__(256) void prep_cb_kernel(const float* __restrict__ cb,
                                                      __bf16* __restrict__ cbh,
                                                      float* __restrict__ csq) {
    int gid  = blockIdx.x * 256 + threadIdx.x;
    int row  = gid >> 6;
    int lane = threadIdx.x & 63;
    float4 v = *reinterpret_cast<const float4*>(cb + (size_t)row * DD + lane * 4);
    bf16x4 h;
    h[0] = (__bf16)v.x; h[1] = (__bf16)v.y; h[2] = (__bf16)v.z; h[3] = (__bf16)v.w;
    int d0 = lane * 4;
    size_t off = (size_t)(row >> 4) * 4096 + (size_t)(d0 >> 5) * 512
               + (size_t)((d0 >> 3) & 3) * 128 + (size_t)(row & 15) * 8 + (d0 & 7);
    *reinterpret_cast<bf16x4*>(cbh + off) = h;
    float ss = v.x * v.x + v.y * v.y + v.z * v.z + v.w * v.w;
#pragma unroll
    for (int m = 1; m < 64; m <<= 1) ss += __shfl_xor(ss, m, 64);
    if (lane == 0) csq[row] = ss;
}

// main: 8 waves/block (512 threads), each wave owns 32 points; all 1024 clusters.
// 16 KB groups (2 K-tiles) per sync; ring of 3 buffers; prefetch depth 2 with
// counted vmcnt(2) + raw s_barrier; setprio around MFMAs.
__global__ __launch_bounds__(512) void kmeans_kernel(const float* __restrict__ x,
                                                     const __bf16* __restrict__ cbp,
                                                     const float* __restrict__ csq,
                                                     unsigned short* __restrict__ bucketg,
                                                     int* __restrict__ counts,
                                                     float* __restrict__ out) {
    __shared__ __bf16 sh[3 * 8192];   // 3 buffers x 16 KB = 48 KB
    __shared__ float  css[KCL];       // 4 KB
    __shared__ int bucket_s[256];
    const int tid  = threadIdx.x;
    const int lane = tid & 63;
    const int wid  = tid >> 6;        // 0..7
    const int l15  = lane & 15;
    const int lg   = lane >> 4;
    const int rowbase = blockIdx.x * 256 + wid * 32;

    // ---- load x tile (32 rows/wave) as bf16 a-frags in regs, fp32 x_sq ----
    bf16x8 A[2][8];
    float xsq_e[2][4];
#pragma unroll
    for (int rt = 0; rt < 2; ++rt) {
        const float* xr = x + (size_t)(rowbase + rt * 16 + l15) * DD + lg * 8;
        float ss = 0.0f;
#pragma unroll
        for (int t = 0; t < 8; ++t) {
            float4 lo = *reinterpret_cast<const float4*>(xr + t * 32);
            float4 hi = *reinterpret_cast<const float4*>(xr + t * 32 + 4);
            ss += lo.x * lo.x + lo.y * lo.y + lo.z * lo.z + lo.w * lo.w;
            ss += hi.x * hi.x + hi.y * hi.y + hi.z * hi.z + hi.w * hi.w;
            bf16x8 a;
            a[0] = (__bf16)lo.x; a[1] = (__bf16)lo.y; a[2] = (__bf16)lo.z; a[3] = (__bf16)lo.w;
            a[4] = (__bf16)hi.x; a[5] = (__bf16)hi.y; a[6] = (__bf16)hi.z; a[7] = (__bf16)hi.w;
            A[rt][t] = a;
        }
        ss += __shfl_xor(ss, 16, 64);
        ss += __shfl_xor(ss, 32, 64);
#pragma unroll
        for (int r = 0; r < 4; ++r) xsq_e[rt][r] = __shfl(ss, lg * 4 + r, 64);
    }

    // stage csq into LDS (1024 floats by 512 threads)
    {
        float2 c2 = *reinterpret_cast<const float2*>(csq + tid * 2);
        *reinterpret_cast<float2*>(css + tid * 2) = c2;
    }

    // packed argmin: low 10 mantissa bits of d2 carry the cluster index
    float minp[2][4];
    float ssum0 = 0.0f, ssum1 = 0.0f;
#pragma unroll
    for (int rt = 0; rt < 2; ++rt)
#pragma unroll
        for (int r = 0; r < 4; ++r) minp[rt][r] = 3.4e38f;

    const char* cbB = (const char*)cbp;
    char* shB = (char*)sh;

    // stage one 16 KB group: 512 threads x 16 B x 2
    auto stage = [&](int G, int buf) {
        const char* src = cbB + (size_t)G * 16384 + tid * 16;
        char* dst = shB + buf * 16384 + tid * 16;
        GLOAD_LDS16(src, dst);
        GLOAD_LDS16(src + 8192, dst + 8192);
    };

    auto compute_subtile = [&](const __bf16* tb, int kt, float cs) {
        bf16x8 B[8];
#pragma unroll
        for (int t = 0; t < 8; ++t)
            B[t] = *reinterpret_cast<const bf16x8*>(tb + (t * 64 + lane) * 8);
        f32x4 a0 = {0.f, 0.f, 0.f, 0.f}, a1 = {0.f, 0.f, 0.f, 0.f};
        f32x4 b0 = {0.f, 0.f, 0.f, 0.f}, b1 = {0.f, 0.f, 0.f, 0.f};
        __builtin_amdgcn_s_setprio(1);
#pragma unroll
        for (int t = 0; t < 4; ++t) {
            a0 = __builtin_amdgcn_mfma_f32_16x16x32_bf16(A[0][t], B[t], a0, 0, 0, 0);
            a1 = __builtin_amdgcn_mfma_f32_16x16x32_bf16(A[1][t], B[t], a1, 0, 0, 0);
        }
#pragma unroll
        for (int t = 4; t < 8; ++t) {
            b0 = __builtin_amdgcn_mfma_f32_16x16x32_bf16(A[0][t], B[t], b0, 0, 0, 0);
            b1 = __builtin_amdgcn_mfma_f32_16x16x32_bf16(A[1][t], B[t], b1, 0, 0, 0);
        }
        __builtin_amdgcn_s_setprio(0);
        const unsigned colb = (unsigned)(kt * 16 + l15);
#pragma unroll
        for (int r = 0; r < 4; ++r) {
            float d2a = fmaf(-2.0f, a0[r] + b0[r], xsq_e[0][r] + cs);
            ssum0 += __builtin_amdgcn_sqrtf(d2a);
            float pa = __uint_as_float((__float_as_uint(d2a) & 0xFFFFFC00u) | colb);
            minp[0][r] = fminf(minp[0][r], pa);
            float d2b = fmaf(-2.0f, a1[r] + b1[r], xsq_e[1][r] + cs);
            ssum1 += __builtin_amdgcn_sqrtf(d2b);
            float pb = __uint_as_float((__float_as_uint(d2b) & 0xFFFFFC00u) | colb);
            minp[1][r] = fminf(minp[1][r], pb);
        }
    };

    // drain prologue (x loads consumed, css/LDS written), sync baseline
    __syncthreads();

    // prologue staging: groups 0,1 into buffers 0,1
    stage(0, 0);
    stage(1, 1);
    asm volatile("s_waitcnt vmcnt(2)" ::: "memory");   // group 0 landed
    __builtin_amdgcn_s_barrier();

#define KM_BODY(G, BG, BS)                                                    \
    {                                                                         \
        stage((G) + 2, (BS));                                                 \
        float cs0 = css[(G) * 32 + l15];                                      \
        float cs1 = css[(G) * 32 + 16 + l15];                                 \
        compute_subtile(sh + (BG) * 8192, (G) * 2, cs0);                      \
        compute_subtile(sh + (BG) * 8192 + 4096, (G) * 2 + 1, cs1);           \
        asm volatile("s_waitcnt vmcnt(2)" ::: "memory");                      \
        __builtin_amdgcn_s_barrier();                                         \
    }

    for (int G = 0; G < 30; G += 3) {
        KM_BODY(G, 0, 2)
        KM_BODY(G + 1, 1, 0)
        KM_BODY(G + 2, 2, 1)
    }
    // tail: group 30 (buf 0), group 31 (buf 1)
    {
        float cs0 = css[30 * 32 + l15];
        float cs1 = css[30 * 32 + 16 + l15];
        compute_subtile(sh + 0 * 8192, 60, cs0);
        compute_subtile(sh + 0 * 8192 + 4096, 61, cs1);
        asm volatile("s_waitcnt vmcnt(0)" ::: "memory");
        __builtin_amdgcn_s_barrier();
        float cs2 = css[31 * 32 + l15];
        float cs3 = css[31 * 32 + 16 + l15];
        compute_subtile(sh + 1 * 8192, 62, cs2);
        compute_subtile(sh + 1 * 8192 + 4096, 63, cs3);
    }
#undef KM_BODY

    // ---- per-row argmin across the 16 lanes of each group: pure fmin reduce ----
#pragma unroll
    for (int rt = 0; rt < 2; ++rt)
#pragma unroll
        for (int r = 0; r < 4; ++r) {
            float v = minp[rt][r];
#pragma unroll
            for (int m = 1; m <= 8; m <<= 1) v = fminf(v, __shfl_xor(v, m, 64));
            if (l15 == 0) bucket_s[wid * 32 + rt * 16 + lg * 4 + r] = (int)(__float_as_uint(v) & 1023u);
        }
    __syncthreads();

    if (tid < 256) {
        int b = bucket_s[tid];
        bucketg[blockIdx.x * 256 + tid] = (unsigned short)b;
        atomicAdd(&counts[b], 1);
    }

    // ---- mean partial ----
    float ssum = ssum0 + ssum1;
#pragma unroll
    for (int m = 1; m < 64; m <<= 1) ssum += __shfl_xor(ssum, m, 64);
    if (lane == 0) atomicAdd(out, ssum * 7.4505805969238281e-9f);  // 1/2^27 exact
}

// single-block Hillis-Steele exclusive scan of the 1024 cluster counts
__global__ __launch_bounds__(1024) void scan_kernel(const int* __restrict__ counts,
                                                    int* __restrict__ offs,
                                                    int* __restrict__ cursor) {
    __shared__ int tmp[1024];
    const int t = threadIdx.x;
    const int v = counts[t];
    tmp[t] = v;
    __syncthreads();
    for (int d = 1; d < 1024; d <<= 1) {
        int a = (t >= d) ? tmp[t - d] : 0;
        __syncthreads();
        tmp[t] += a;
        __syncthreads();
    }
    const int excl = tmp[t] - v;
    offs[t] = excl;
    cursor[t] = excl;
    if (t == 1023) offs[1024] = tmp[t];
}

// place point indices into cluster-sorted order; also record cluster per position
__global__ __launch_bounds__(256) void scatter_kernel(const unsigned short* __restrict__ bucket,
                                                      int* __restrict__ cursor,
                                                      int* __restrict__ sorted,
                                                      unsigned short* __restrict__ clpos) {
    int i = blockIdx.x * 256 + threadIdx.x;
    int b = bucket[i];
    int pos = atomicAdd(&cursor[b], 1);
    sorted[pos] = i;
    clpos[pos] = (unsigned short)b;
}

// point-parallel segmented reduction over cluster-sorted order.
__global__ __launch_bounds__(256) void gather_kernel(const float* __restrict__ x,
                                                     const int* __restrict__ sorted,
                                                     const unsigned short* __restrict__ clpos,
                                                     float* __restrict__ out) {
    const int lane = threadIdx.x & 63;
    const int wv   = blockIdx.x * 4 + (threadIdx.x >> 6);
    const int pbeg = wv * 128;
    float* bins = out + 1;
    float* nums = out + 1 + KCL * DD;

    float4 acc = {0.f, 0.f, 0.f, 0.f};
    int cur = clpos[pbeg];
    int seglen = 0;

    auto flush = [&](int nextc) {
        float* bp = bins + (size_t)cur * DD + lane * 4;
        atomicAdd(bp + 0, acc.x);
        atomicAdd(bp + 1, acc.y);
        atomicAdd(bp + 2, acc.z);
        atomicAdd(bp + 3, acc.w);
        if (lane == 0) atomicAdd(nums + cur, (float)seglen);
        acc.x = 0.f; acc.y = 0.f; acc.z = 0.f; acc.w = 0.f;
        seglen = 0;
        cur = nextc;
    };

    int rowA[8], rowB[8];
    int clsA[8], clsB[8];
#pragma unroll
    for (int i = 0; i < 8; ++i) { rowA[i] = sorted[pbeg + i]; clsA[i] = clpos[pbeg + i]; }

    for (int g = 0; g < 128; g += 16) {
#pragma unroll
        for (int i = 0; i < 8; ++i) {
            rowB[i] = sorted[pbeg + g + 8 + i];
            clsB[i] = clpos[pbeg + g + 8 + i];
        }
        {
            float4 v[8];
#pragma unroll
            for (int i = 0; i < 8; ++i)
                v[i] = *reinterpret_cast<const float4*>(x + (size_t)rowA[i] * DD + lane * 4);
#pragma unroll
            for (int i = 0; i < 8; ++i) {
                if (clsA[i] != cur) flush(clsA[i]);
                acc.x += v[i].x; acc.y += v[i].y; acc.z += v[i].z; acc.w += v[i].w;
                ++seglen;
            }
        }
        if (g + 16 < 128) {
#pragma unroll
            for (int i = 0; i < 8; ++i) {
                rowA[i] = sorted[pbeg + g + 16 + i];
                clsA[i] = clpos[pbeg + g + 16 + i];
            }
        }
        {
            float4 v[8];
#pragma unroll
            for (int i = 0; i < 8; ++i)
                v[i] = *reinterpret_cast<const float4*>(x + (size_t)rowB[i] * DD + lane * 4);
#pragma unroll
            for (int i = 0; i < 8; ++i) {
                if (clsB[i] != cur) flush(clsB[i]);
                acc.x += v[i].x; acc.y += v[i].y; acc.z += v[i].z; acc.w += v[i].w;
                ++seglen;
            }
        }
    }
    flush(0);
}

extern "C" void kernel_launch(void* const* d_in, const int* in_sizes, int n_in,
                              void* d_out, int out_size, void* d_ws, size_t ws_size,
                              hipStream_t stream) {
    const float* x    = (const float*)d_in[0];
    const float* cb   = (const float*)d_in[1];
    const float* bins = (const float*)d_in[2];
    const float* nums = (const float*)d_in[3];
    float* out = (float*)d_out;

    char* ws = (char*)d_ws;
    __bf16*         cbp    = (__bf16*)ws;                        // 512 KB permuted (dead after kmeans)
    float*          csq    = (float*)(ws + 512 * 1024);          // 4 KB
    unsigned short* bucket = (unsigned short*)(ws + 516 * 1024); // 256 KB
    int*            counts = (int*)(ws + 772 * 1024);            // 4 KB
    int*            offs   = (int*)(ws + 776 * 1024);            // 4 KB + 4
    int*            cursor = (int*)(ws + 781 * 1024);            // 4 KB
    unsigned short* clpos  = (unsigned short*)(ws + 785 * 1024); // 256 KB
    int*            sorted = (int*)cbp;                           // aliases cbp, 512 KB

    init_out_kernel<<<(1 + KCL * DD + KCL + 255) / 256, 256, 0, stream>>>(bins, nums, out, counts);
    prep_cb_kernel<<<KCL / 4, 256, 0, stream>>>(cb, cbp, csq);
    kmeans_kernel<<<NPTS / 256, 512, 0, stream>>>(x, cbp, csq, bucket, counts, out);
    scan_kernel<<<1, 1024, 0, stream>>>(counts, offs, cursor);
    scatter_kernel<<<NPTS / 256, 256, 0, stream>>>(bucket, cursor, sorted, clpos);
    gather_kernel<<<NPTS / 512, 256, 0, stream>>>(x, sorted, clpos, out);
}

// Round 10
// 239.112 us; speedup vs baseline: 1.0655x; 1.0338x over previous
//
#include <hip/hip_runtime.h>
#include <hip/hip_bf16.h>

#define NPTS 131072
#define KCL  1024
#define DD   256

typedef __bf16 bf16x8 __attribute__((ext_vector_type(8)));
typedef __bf16 bf16x4 __attribute__((ext_vector_type(4)));
typedef float  f32x4  __attribute__((ext_vector_type(4)));

#define GLOAD_LDS16(gsrc, ldst)                                                             \
    __builtin_amdgcn_global_load_lds(                                                       \
        (const __attribute__((address_space(1))) unsigned int*)(gsrc),                      \
        (__attribute__((address_space(3))) unsigned int*)(ldst), 16, 0, 0)

// Fused: out init (mean/bins/nums), counts zero, codebook bf16 permute, csq.
// Permuted layout: element (cluster c, dim d) with tile=c>>4, cl=c&15,
// t=d>>5, lg=(d>>3)&3, j=d&7  ->  cbh[tile*4096 + t*512 + lg*128 + cl*8 + j]
__global__ __launch_bounds__(256) void setup_kernel(const float* __restrict__ cb,
                                                    const float* __restrict__ bins_in,
                                                    const float* __restrict__ nums_in,
                                                    float* __restrict__ out,
                                                    int* __restrict__ counts,
                                                    __bf16* __restrict__ cbh,
                                                    float* __restrict__ csq) {
    int i = blockIdx.x * 256 + threadIdx.x;
    if (i == 0) out[0] = 0.0f;
    if (i < KCL * DD) out[1 + i] = bins_in[i];
    if (i < KCL) { out[1 + KCL * DD + i] = nums_in[i]; counts[i] = 0; }
    if (i < KCL * 64) {
        int row  = i >> 6;
        int lane = i & 63;
        float4 v = *reinterpret_cast<const float4*>(cb + (size_t)row * DD + lane * 4);
        bf16x4 h;
        h[0] = (__bf16)v.x; h[1] = (__bf16)v.y; h[2] = (__bf16)v.z; h[3] = (__bf16)v.w;
        int d0 = lane * 4;
        size_t off = (size_t)(row >> 4) * 4096 + (size_t)(d0 >> 5) * 512
                   + (size_t)((d0 >> 3) & 3) * 128 + (size_t)(row & 15) * 8 + (d0 & 7);
        *reinterpret_cast<bf16x4*>(cbh + off) = h;
        float ss = v.x * v.x + v.y * v.y + v.z * v.z + v.w * v.w;
#pragma unroll
        for (int m = 1; m < 64; m <<= 1) ss += __shfl_xor(ss, m, 64);
        if (lane == 0) csq[row] = ss;
    }
}

// main: 4 waves/block, each wave owns 32 points; all 1024 clusters.
// 16 KB groups (2 K-tiles) per sync; ring of 3 buffers; prefetch depth 2 with
// counted vmcnt(4) + raw s_barrier; setprio around MFMAs; csq via register
// rotation (prefetched one group ahead); LDS = 48 KB -> 3 blocks/CU.
__global__ __launch_bounds__(256) void kmeans_kernel(const float* __restrict__ x,
                                                     const __bf16* __restrict__ cbp,
                                                     const float* __restrict__ csq,
                                                     unsigned short* __restrict__ bucketg,
                                                     int* __restrict__ counts,
                                                     float* __restrict__ out) {
    __shared__ __bf16 sh[3 * 8192];   // 3 buffers x 16 KB = 48 KB (nothing else!)
    const int tid  = threadIdx.x;
    const int lane = tid & 63;
    const int wid  = tid >> 6;
    const int l15  = lane & 15;
    const int lg   = lane >> 4;
    const int rowbase = blockIdx.x * 128 + wid * 32;

    // ---- load x tile as bf16 a-frags (held in regs), fp32 x_sq on the fly ----
    bf16x8 A[2][8];
    float xsq_e[2][4];
#pragma unroll
    for (int rt = 0; rt < 2; ++rt) {
        const float* xr = x + (size_t)(rowbase + rt * 16 + l15) * DD + lg * 8;
        float ss = 0.0f;
#pragma unroll
        for (int t = 0; t < 8; ++t) {
            float4 lo = *reinterpret_cast<const float4*>(xr + t * 32);
            float4 hi = *reinterpret_cast<const float4*>(xr + t * 32 + 4);
            ss += lo.x * lo.x + lo.y * lo.y + lo.z * lo.z + lo.w * lo.w;
            ss += hi.x * hi.x + hi.y * hi.y + hi.z * hi.z + hi.w * hi.w;
            bf16x8 a;
            a[0] = (__bf16)lo.x; a[1] = (__bf16)lo.y; a[2] = (__bf16)lo.z; a[3] = (__bf16)lo.w;
            a[4] = (__bf16)hi.x; a[5] = (__bf16)hi.y; a[6] = (__bf16)hi.z; a[7] = (__bf16)hi.w;
            A[rt][t] = a;
        }
        ss += __shfl_xor(ss, 16, 64);
        ss += __shfl_xor(ss, 32, 64);
#pragma unroll
        for (int r = 0; r < 4; ++r) xsq_e[rt][r] = __shfl(ss, lg * 4 + r, 64);
    }

    // packed argmin: low 10 mantissa bits of d2 carry the cluster index
    float minp[2][4];
    float ssum0 = 0.0f, ssum1 = 0.0f;
#pragma unroll
    for (int rt = 0; rt < 2; ++rt)
#pragma unroll
        for (int r = 0; r < 4; ++r) minp[rt][r] = 3.4e38f;

    const char* cbB = (const char*)cbp;
    char* shB = (char*)sh;

    // stage one 16 KB group: 256 threads x 16 B x 4
    auto stage = [&](int G, int buf) {
        const char* src = cbB + (size_t)G * 16384 + tid * 16;
        char* dst = shB + buf * 16384 + tid * 16;
        GLOAD_LDS16(src, dst);
        GLOAD_LDS16(src + 4096, dst + 4096);
        GLOAD_LDS16(src + 8192, dst + 8192);
        GLOAD_LDS16(src + 12288, dst + 12288);
    };

    auto compute_subtile = [&](const __bf16* tb, int kt, float cs) {
        bf16x8 B[8];
#pragma unroll
        for (int t = 0; t < 8; ++t)
            B[t] = *reinterpret_cast<const bf16x8*>(tb + (t * 64 + lane) * 8);
        f32x4 a0 = {0.f, 0.f, 0.f, 0.f}, a1 = {0.f, 0.f, 0.f, 0.f};
        f32x4 b0 = {0.f, 0.f, 0.f, 0.f}, b1 = {0.f, 0.f, 0.f, 0.f};
        __builtin_amdgcn_s_setprio(1);
#pragma unroll
        for (int t = 0; t < 4; ++t) {
            a0 = __builtin_amdgcn_mfma_f32_16x16x32_bf16(A[0][t], B[t], a0, 0, 0, 0);
            a1 = __builtin_amdgcn_mfma_f32_16x16x32_bf16(A[1][t], B[t], a1, 0, 0, 0);
        }
#pragma unroll
        for (int t = 4; t < 8; ++t) {
            b0 = __builtin_amdgcn_mfma_f32_16x16x32_bf16(A[0][t], B[t], b0, 0, 0, 0);
            b1 = __builtin_amdgcn_mfma_f32_16x16x32_bf16(A[1][t], B[t], b1, 0, 0, 0);
        }
        __builtin_amdgcn_s_setprio(0);
        const unsigned colb = (unsigned)(kt * 16 + l15);
#pragma unroll
        for (int r = 0; r < 4; ++r) {
            float d2a = fmaf(-2.0f, a0[r] + b0[r], xsq_e[0][r] + cs);
            ssum0 += __builtin_amdgcn_sqrtf(d2a);
            float pa = __uint_as_float((__float_as_uint(d2a) & 0xFFFFFC00u) | colb);
            minp[0][r] = fminf(minp[0][r], pa);
            float d2b = fmaf(-2.0f, a1[r] + b1[r], xsq_e[1][r] + cs);
            ssum1 += __builtin_amdgcn_sqrtf(d2b);
            float pb = __uint_as_float((__float_as_uint(d2b) & 0xFFFFFC00u) | colb);
            minp[1][r] = fminf(minp[1][r], pb);
        }
    };

    // csq register rotation: csA = current group's two column-sums
    float csA0 = csq[l15];
    float csA1 = csq[16 + l15];

    // sync wave start (x loads already consumed by conversion)
    __syncthreads();

    // prologue staging: groups 0,1 into buffers 0,1
    stage(0, 0);
    stage(1, 1);
    asm volatile("s_waitcnt vmcnt(4)" ::: "memory");   // group 0 landed
    __builtin_amdgcn_s_barrier();

#define KM_BODY(G, BG, BS)                                                    \
    {                                                                         \
        float csB0 = csq[((G) + 1) * 32 + l15];                               \
        float csB1 = csq[((G) + 1) * 32 + 16 + l15];                          \
        stage((G) + 2, (BS));                                                 \
        compute_subtile(sh + (BG) * 8192, (G) * 2, csA0);                     \
        compute_subtile(sh + (BG) * 8192 + 4096, (G) * 2 + 1, csA1);          \
        asm volatile("s_waitcnt vmcnt(4)" ::: "memory");                      \
        __builtin_amdgcn_s_barrier();                                         \
        csA0 = csB0; csA1 = csB1;                                             \
    }

    for (int G = 0; G < 30; G += 3) {
        KM_BODY(G, 0, 2)
        KM_BODY(G + 1, 1, 0)
        KM_BODY(G + 2, 2, 1)
    }
    // tail: group 30 (buf 0), group 31 (buf 1)
    {
        float csB0 = csq[31 * 32 + l15];
        float csB1 = csq[31 * 32 + 16 + l15];
        compute_subtile(sh + 0 * 8192, 60, csA0);
        compute_subtile(sh + 0 * 8192 + 4096, 61, csA1);
        asm volatile("s_waitcnt vmcnt(0)" ::: "memory");
        __builtin_amdgcn_s_barrier();
        compute_subtile(sh + 1 * 8192, 62, csB0);
        compute_subtile(sh + 1 * 8192 + 4096, 63, csB1);
    }
#undef KM_BODY

    // ---- per-row argmin across 16 lanes; reducing lane writes directly ----
#pragma unroll
    for (int rt = 0; rt < 2; ++rt)
#pragma unroll
        for (int r = 0; r < 4; ++r) {
            float v = minp[rt][r];
#pragma unroll
            for (int m = 1; m <= 8; m <<= 1) v = fminf(v, __shfl_xor(v, m, 64));
            if (l15 == 0) {
                int b = (int)(__float_as_uint(v) & 1023u);
                int row = wid * 32 + rt * 16 + lg * 4 + r;
                bucketg[blockIdx.x * 128 + row] = (unsigned short)b;
                atomicAdd(&counts[b], 1);
            }
        }

    // ---- mean partial ----
    float ssum = ssum0 + ssum1;
#pragma unroll
    for (int m = 1; m < 64; m <<= 1) ssum += __shfl_xor(ssum, m, 64);
    if (lane == 0) atomicAdd(out, ssum * 7.4505805969238281e-9f);  // 1/2^27 exact
}

// shuffle-based exclusive scan of the 1024 cluster counts (2 barriers)
__global__ __launch_bounds__(1024) void scan_kernel(const int* __restrict__ counts,
                                                    int* __restrict__ offs,
                                                    int* __restrict__ cursor) {
    __shared__ int wsum[16];
    const int t = threadIdx.x;
    const int lane = t & 63;
    const int w = t >> 6;
    const int v = counts[t];
    int s = v;
#pragma unroll
    for (int d = 1; d < 64; d <<= 1) {
        int o = __shfl_up(s, d, 64);
        if (lane >= d) s += o;
    }
    if (lane == 63) wsum[w] = s;
    __syncthreads();
    if (w == 0) {
        int ws_ = (lane < 16) ? wsum[lane] : 0;
#pragma unroll
        for (int d = 1; d < 16; d <<= 1) {
            int o = __shfl_up(ws_, d, 64);
            if (lane >= d) ws_ += o;
        }
        if (lane < 16) wsum[lane] = ws_;
    }
    __syncthreads();
    const int base = (w > 0) ? wsum[w - 1] : 0;
    const int incl = base + s;
    const int excl = incl - v;
    offs[t] = excl;
    cursor[t] = excl;
    if (t == 1023) offs[1024] = incl;
}

// place point indices into cluster-sorted order; also record cluster per position
__global__ __launch_bounds__(256) void scatter_kernel(const unsigned short* __restrict__ bucket,
                                                      int* __restrict__ cursor,
                                                      int* __restrict__ sorted,
                                                      unsigned short* __restrict__ clpos) {
    int i = blockIdx.x * 256 + threadIdx.x;
    int b = bucket[i];
    int pos = atomicAdd(&cursor[b], 1);
    sorted[pos] = i;
    clpos[pos] = (unsigned short)b;
}

// point-parallel segmented reduction over cluster-sorted order.
__global__ __launch_bounds__(256) void gather_kernel(const float* __restrict__ x,
                                                     const int* __restrict__ sorted,
                                                     const unsigned short* __restrict__ clpos,
                                                     float* __restrict__ out) {
    const int lane = threadIdx.x & 63;
    const int wv   = blockIdx.x * 4 + (threadIdx.x >> 6);
    const int pbeg = wv * 128;
    float* bins = out + 1;
    float* nums = out + 1 + KCL * DD;

    float4 acc = {0.f, 0.f, 0.f, 0.f};
    int cur = clpos[pbeg];
    int seglen = 0;

    auto flush = [&](int nextc) {
        float* bp = bins + (size_t)cur * DD + lane * 4;
        atomicAdd(bp + 0, acc.x);
        atomicAdd(bp + 1, acc.y);
        atomicAdd(bp + 2, acc.z);
        atomicAdd(bp + 3, acc.w);
        if (lane == 0) atomicAdd(nums + cur, (float)seglen);
        acc.x = 0.f; acc.y = 0.f; acc.z = 0.f; acc.w = 0.f;
        seglen = 0;
        cur = nextc;
    };

    int rowA[8], rowB[8];
    int clsA[8], clsB[8];
#pragma unroll
    for (int i = 0; i < 8; ++i) { rowA[i] = sorted[pbeg + i]; clsA[i] = clpos[pbeg + i]; }

    for (int g = 0; g < 128; g += 16) {
#pragma unroll
        for (int i = 0; i < 8; ++i) {
            rowB[i] = sorted[pbeg + g + 8 + i];
            clsB[i] = clpos[pbeg + g + 8 + i];
        }
        {
            float4 v[8];
#pragma unroll
            for (int i = 0; i < 8; ++i)
                v[i] = *reinterpret_cast<const float4*>(x + (size_t)rowA[i] * DD + lane * 4);
#pragma unroll
            for (int i = 0; i < 8; ++i) {
                if (clsA[i] != cur) flush(clsA[i]);
                acc.x += v[i].x; acc.y += v[i].y; acc.z += v[i].z; acc.w += v[i].w;
                ++seglen;
            }
        }
        if (g + 16 < 128) {
#pragma unroll
            for (int i = 0; i < 8; ++i) {
                rowA[i] = sorted[pbeg + g + 16 + i];
                clsA[i] = clpos[pbeg + g + 16 + i];
            }
        }
        {
            float4 v[8];
#pragma unroll
            for (int i = 0; i < 8; ++i)
                v[i] = *reinterpret_cast<const float4*>(x + (size_t)rowB[i] * DD + lane * 4);
#pragma unroll
            for (int i = 0; i < 8; ++i) {
                if (clsB[i] != cur) flush(clsB[i]);
                acc.x += v[i].x; acc.y += v[i].y; acc.z += v[i].z; acc.w += v[i].w;
                ++seglen;
            }
        }
    }
    flush(0);
}

extern "C" void kernel_launch(void* const* d_in, const int* in_sizes, int n_in,
                              void* d_out, int out_size, void* d_ws, size_t ws_size,
                              hipStream_t stream) {
    const float* x    = (const float*)d_in[0];
    const float* cb   = (const float*)d_in[1];
    const float* bins = (const float*)d_in[2];
    const float* nums = (const float*)d_in[3];
    float* out = (float*)d_out;

    char* ws = (char*)d_ws;
    __bf16*         cbp    = (__bf16*)ws;                        // 512 KB permuted (dead after kmeans)
    float*          csq    = (float*)(ws + 512 * 1024);          // 4 KB
    unsigned short* bucket = (unsigned short*)(ws + 516 * 1024); // 256 KB
    int*            counts = (int*)(ws + 772 * 1024);            // 4 KB
    int*            offs   = (int*)(ws + 776 * 1024);            // 4 KB + 4
    int*            cursor = (int*)(ws + 781 * 1024);            // 4 KB
    unsigned short* clpos  = (unsigned short*)(ws + 785 * 1024); // 256 KB
    int*            sorted = (int*)cbp;                           // aliases cbp, 512 KB

    setup_kernel<<<1029, 256, 0, stream>>>(cb, bins, nums, out, counts, cbp, csq);
    kmeans_kernel<<<NPTS / 128, 256, 0, stream>>>(x, cbp, csq, bucket, counts, out);
    scan_kernel<<<1, 1024, 0, stream>>>(counts, offs, cursor);
    scatter_kernel<<<NPTS / 256, 256, 0, stream>>>(bucket, cursor, sorted, clpos);
    gather_kernel<<<NPTS / 512, 256, 0, stream>>>(x, sorted, clpos, out);
}

// Round 11
// 223.122 us; speedup vs baseline: 1.1418x; 1.0717x over previous
//
#include <hip/hip_runtime.h>
#include <hip/hip_bf16.h>

#define NPTS 131072
#define KCL  1024
#define DD   256

typedef __bf16 bf16x8 __attribute__((ext_vector_type(8)));
typedef __bf16 bf16x4 __attribute__((ext_vector_type(4)));
typedef float  f32x4  __attribute__((ext_vector_type(4)));

#define GLOAD_LDS16(gsrc, ldst)                                                             \
    __builtin_amdgcn_global_load_lds(                                                       \
        (const __attribute__((address_space(1))) unsigned int*)(gsrc),                      \
        (__attribute__((address_space(3))) unsigned int*)(ldst), 16, 0, 0)

// Fused: out init (mean/bins/nums), counts zero, codebook bf16 permute, csq.
// Permuted layout: element (cluster c, dim d) with tile=c>>4, cl=c&15,
// t=d>>5, lg=(d>>3)&3, j=d&7  ->  cbh[tile*4096 + t*512 + lg*128 + cl*8 + j]
__global__ __launch_bounds__(256) void setup_kernel(const float* __restrict__ cb,
                                                    const float* __restrict__ bins_in,
                                                    const float* __restrict__ nums_in,
                                                    float* __restrict__ out,
                                                    int* __restrict__ counts,
                                                    __bf16* __restrict__ cbh,
                                                    float* __restrict__ csq) {
    int i = blockIdx.x * 256 + threadIdx.x;
    if (i == 0) out[0] = 0.0f;
    if (i < KCL * DD) out[1 + i] = bins_in[i];
    if (i < KCL) { out[1 + KCL * DD + i] = nums_in[i]; counts[i] = 0; }
    if (i < KCL * 64) {
        int row  = i >> 6;
        int lane = i & 63;
        float4 v = *reinterpret_cast<const float4*>(cb + (size_t)row * DD + lane * 4);
        bf16x4 h;
        h[0] = (__bf16)v.x; h[1] = (__bf16)v.y; h[2] = (__bf16)v.z; h[3] = (__bf16)v.w;
        int d0 = lane * 4;
        size_t off = (size_t)(row >> 4) * 4096 + (size_t)(d0 >> 5) * 512
                   + (size_t)((d0 >> 3) & 3) * 128 + (size_t)(row & 15) * 8 + (d0 & 7);
        *reinterpret_cast<bf16x4*>(cbh + off) = h;
        float ss = v.x * v.x + v.y * v.y + v.z * v.z + v.w * v.w;
#pragma unroll
        for (int m = 1; m < 64; m <<= 1) ss += __shfl_xor(ss, m, 64);
        if (lane == 0) csq[row] = ss;
    }
}

// main: 4 waves/block, each wave owns 32 points; loops all 1024 clusters.
// EXACT round-7 structure (best measured: 145 us): 16 KB groups (2 K-tiles)
// per sync; ring of 3 buffers; prefetch depth 2 with counted vmcnt(4) + raw
// s_barrier; 4 MFMA chains; setprio around MFMAs; css staged in LDS.
__global__ __launch_bounds__(256) void kmeans_kernel(const float* __restrict__ x,
                                                     const __bf16* __restrict__ cbp,
                                                     const float* __restrict__ csq,
                                                     unsigned short* __restrict__ bucketg,
                                                     int* __restrict__ counts,
                                                     float* __restrict__ out) {
    __shared__ __bf16 sh[3 * 8192];   // 3 buffers x 16 KB = 48 KB
    __shared__ float  css[KCL];       // 4 KB
    __shared__ int bucket_s[128];
    const int tid  = threadIdx.x;
    const int lane = tid & 63;
    const int wid  = tid >> 6;
    const int l15  = lane & 15;
    const int lg   = lane >> 4;
    const int rowbase = blockIdx.x * 128 + wid * 32;

    // ---- load x tile as bf16 a-frags (held in regs), fp32 x_sq on the fly ----
    bf16x8 A[2][8];
    float xsq_e[2][4];
#pragma unroll
    for (int rt = 0; rt < 2; ++rt) {
        const float* xr = x + (size_t)(rowbase + rt * 16 + l15) * DD + lg * 8;
        float ss = 0.0f;
#pragma unroll
        for (int t = 0; t < 8; ++t) {
            float4 lo = *reinterpret_cast<const float4*>(xr + t * 32);
            float4 hi = *reinterpret_cast<const float4*>(xr + t * 32 + 4);
            ss += lo.x * lo.x + lo.y * lo.y + lo.z * lo.z + lo.w * lo.w;
            ss += hi.x * hi.x + hi.y * hi.y + hi.z * hi.z + hi.w * hi.w;
            bf16x8 a;
            a[0] = (__bf16)lo.x; a[1] = (__bf16)lo.y; a[2] = (__bf16)lo.z; a[3] = (__bf16)lo.w;
            a[4] = (__bf16)hi.x; a[5] = (__bf16)hi.y; a[6] = (__bf16)hi.z; a[7] = (__bf16)hi.w;
            A[rt][t] = a;
        }
        ss += __shfl_xor(ss, 16, 64);
        ss += __shfl_xor(ss, 32, 64);
#pragma unroll
        for (int r = 0; r < 4; ++r) xsq_e[rt][r] = __shfl(ss, lg * 4 + r, 64);
    }

    // stage csq into LDS (1024 floats by 256 threads)
    {
        float4 c4 = *reinterpret_cast<const float4*>(csq + tid * 4);
        *reinterpret_cast<float4*>(css + tid * 4) = c4;
    }

    // packed argmin: low 10 mantissa bits of d2 carry the cluster index
    float minp[2][4];
    float ssum0 = 0.0f, ssum1 = 0.0f;
#pragma unroll
    for (int rt = 0; rt < 2; ++rt)
#pragma unroll
        for (int r = 0; r < 4; ++r) minp[rt][r] = 3.4e38f;

    const char* cbB = (const char*)cbp;
    char* shB = (char*)sh;

    // stage one 16 KB group: 256 threads x 16 B x 4
    auto stage = [&](int G, int buf) {
        const char* src = cbB + (size_t)G * 16384 + tid * 16;
        char* dst = shB + buf * 16384 + tid * 16;
        GLOAD_LDS16(src, dst);
        GLOAD_LDS16(src + 4096, dst + 4096);
        GLOAD_LDS16(src + 8192, dst + 8192);
        GLOAD_LDS16(src + 12288, dst + 12288);
    };

    auto compute_subtile = [&](const __bf16* tb, int kt, float cs) {
        bf16x8 B[8];
#pragma unroll
        for (int t = 0; t < 8; ++t)
            B[t] = *reinterpret_cast<const bf16x8*>(tb + (t * 64 + lane) * 8);
        f32x4 a0 = {0.f, 0.f, 0.f, 0.f}, a1 = {0.f, 0.f, 0.f, 0.f};
        f32x4 b0 = {0.f, 0.f, 0.f, 0.f}, b1 = {0.f, 0.f, 0.f, 0.f};
        __builtin_amdgcn_s_setprio(1);
#pragma unroll
        for (int t = 0; t < 4; ++t) {
            a0 = __builtin_amdgcn_mfma_f32_16x16x32_bf16(A[0][t], B[t], a0, 0, 0, 0);
            a1 = __builtin_amdgcn_mfma_f32_16x16x32_bf16(A[1][t], B[t], a1, 0, 0, 0);
        }
#pragma unroll
        for (int t = 4; t < 8; ++t) {
            b0 = __builtin_amdgcn_mfma_f32_16x16x32_bf16(A[0][t], B[t], b0, 0, 0, 0);
            b1 = __builtin_amdgcn_mfma_f32_16x16x32_bf16(A[1][t], B[t], b1, 0, 0, 0);
        }
        __builtin_amdgcn_s_setprio(0);
        const unsigned colb = (unsigned)(kt * 16 + l15);
#pragma unroll
        for (int r = 0; r < 4; ++r) {
            float d2a = fmaf(-2.0f, a0[r] + b0[r], xsq_e[0][r] + cs);
            ssum0 += __builtin_amdgcn_sqrtf(d2a);
            float pa = __uint_as_float((__float_as_uint(d2a) & 0xFFFFFC00u) | colb);
            minp[0][r] = fminf(minp[0][r], pa);
            float d2b = fmaf(-2.0f, a1[r] + b1[r], xsq_e[1][r] + cs);
            ssum1 += __builtin_amdgcn_sqrtf(d2b);
            float pb = __uint_as_float((__float_as_uint(d2b) & 0xFFFFFC00u) | colb);
            minp[1][r] = fminf(minp[1][r], pb);
        }
    };

    // drain prologue (x loads consumed, css/LDS written), sync baseline
    __syncthreads();

    // prologue staging: groups 0,1 into buffers 0,1
    stage(0, 0);
    stage(1, 1);
    asm volatile("s_waitcnt vmcnt(4)" ::: "memory");   // group 0 landed
    __builtin_amdgcn_s_barrier();

#define KM_BODY(G, BG, BS)                                                    \
    {                                                                         \
        stage((G) + 2, (BS));                                                 \
        float cs0 = css[(G) * 32 + l15];                                      \
        float cs1 = css[(G) * 32 + 16 + l15];                                 \
        compute_subtile(sh + (BG) * 8192, (G) * 2, cs0);                      \
        compute_subtile(sh + (BG) * 8192 + 4096, (G) * 2 + 1, cs1);           \
        asm volatile("s_waitcnt vmcnt(4)" ::: "memory");                      \
        __builtin_amdgcn_s_barrier();                                         \
    }

    for (int G = 0; G < 30; G += 3) {
        KM_BODY(G, 0, 2)
        KM_BODY(G + 1, 1, 0)
        KM_BODY(G + 2, 2, 1)
    }
    // tail: group 30 (buf 0), group 31 (buf 1)
    {
        float cs0 = css[30 * 32 + l15];
        float cs1 = css[30 * 32 + 16 + l15];
        compute_subtile(sh + 0 * 8192, 60, cs0);
        compute_subtile(sh + 0 * 8192 + 4096, 61, cs1);
        asm volatile("s_waitcnt vmcnt(0)" ::: "memory");
        __builtin_amdgcn_s_barrier();
        float cs2 = css[31 * 32 + l15];
        float cs3 = css[31 * 32 + 16 + l15];
        compute_subtile(sh + 1 * 8192, 62, cs2);
        compute_subtile(sh + 1 * 8192 + 4096, 63, cs3);
    }
#undef KM_BODY

    // ---- per-row argmin across the 16 lanes of each group: pure fmin reduce ----
#pragma unroll
    for (int rt = 0; rt < 2; ++rt)
#pragma unroll
        for (int r = 0; r < 4; ++r) {
            float v = minp[rt][r];
#pragma unroll
            for (int m = 1; m <= 8; m <<= 1) v = fminf(v, __shfl_xor(v, m, 64));
            if (l15 == 0) bucket_s[wid * 32 + rt * 16 + lg * 4 + r] = (int)(__float_as_uint(v) & 1023u);
        }
    __syncthreads();

    if (tid < 128) {
        int b = bucket_s[tid];
        bucketg[blockIdx.x * 128 + tid] = (unsigned short)b;
        atomicAdd(&counts[b], 1);
    }

    // ---- mean partial ----
    float ssum = ssum0 + ssum1;
#pragma unroll
    for (int m = 1; m < 64; m <<= 1) ssum += __shfl_xor(ssum, m, 64);
    if (lane == 0) atomicAdd(out, ssum * 7.4505805969238281e-9f);  // 1/2^27 exact
}

// shuffle-based exclusive scan of the 1024 cluster counts (2 barriers)
__global__ __launch_bounds__(1024) void scan_kernel(const int* __restrict__ counts,
                                                    int* __restrict__ offs,
                                                    int* __restrict__ cursor) {
    __shared__ int wsum[16];
    const int t = threadIdx.x;
    const int lane = t & 63;
    const int w = t >> 6;
    const int v = counts[t];
    int s = v;
#pragma unroll
    for (int d = 1; d < 64; d <<= 1) {
        int o = __shfl_up(s, d, 64);
        if (lane >= d) s += o;
    }
    if (lane == 63) wsum[w] = s;
    __syncthreads();
    if (w == 0) {
        int ws_ = (lane < 16) ? wsum[lane] : 0;
#pragma unroll
        for (int d = 1; d < 16; d <<= 1) {
            int o = __shfl_up(ws_, d, 64);
            if (lane >= d) ws_ += o;
        }
        if (lane < 16) wsum[lane] = ws_;
    }
    __syncthreads();
    const int base = (w > 0) ? wsum[w - 1] : 0;
    const int incl = base + s;
    const int excl = incl - v;
    offs[t] = excl;
    cursor[t] = excl;
    if (t == 1023) offs[1024] = incl;
}

// place point indices into cluster-sorted order; also record cluster per position
__global__ __launch_bounds__(256) void scatter_kernel(const unsigned short* __restrict__ bucket,
                                                      int* __restrict__ cursor,
                                                      int* __restrict__ sorted,
                                                      unsigned short* __restrict__ clpos) {
    int i = blockIdx.x * 256 + threadIdx.x;
    int b = bucket[i];
    int pos = atomicAdd(&cursor[b], 1);
    sorted[pos] = i;
    clpos[pos] = (unsigned short)b;
}

// point-parallel segmented reduction over cluster-sorted order.
__global__ __launch_bounds__(256) void gather_kernel(const float* __restrict__ x,
                                                     const int* __restrict__ sorted,
                                                     const unsigned short* __restrict__ clpos,
                                                     float* __restrict__ out) {
    const int lane = threadIdx.x & 63;
    const int wv   = blockIdx.x * 4 + (threadIdx.x >> 6);
    const int pbeg = wv * 128;
    float* bins = out + 1;
    float* nums = out + 1 + KCL * DD;

    float4 acc = {0.f, 0.f, 0.f, 0.f};
    int cur = clpos[pbeg];
    int seglen = 0;

    auto flush = [&](int nextc) {
        float* bp = bins + (size_t)cur * DD + lane * 4;
        atomicAdd(bp + 0, acc.x);
        atomicAdd(bp + 1, acc.y);
        atomicAdd(bp + 2, acc.z);
        atomicAdd(bp + 3, acc.w);
        if (lane == 0) atomicAdd(nums + cur, (float)seglen);
        acc.x = 0.f; acc.y = 0.f; acc.z = 0.f; acc.w = 0.f;
        seglen = 0;
        cur = nextc;
    };

    int rowA[8], rowB[8];
    int clsA[8], clsB[8];
#pragma unroll
    for (int i = 0; i < 8; ++i) { rowA[i] = sorted[pbeg + i]; clsA[i] = clpos[pbeg + i]; }

    for (int g = 0; g < 128; g += 16) {
#pragma unroll
        for (int i = 0; i < 8; ++i) {
            rowB[i] = sorted[pbeg + g + 8 + i];
            clsB[i] = clpos[pbeg + g + 8 + i];
        }
        {
            float4 v[8];
#pragma unroll
            for (int i = 0; i < 8; ++i)
                v[i] = *reinterpret_cast<const float4*>(x + (size_t)rowA[i] * DD + lane * 4);
#pragma unroll
            for (int i = 0; i < 8; ++i) {
                if (clsA[i] != cur) flush(clsA[i]);
                acc.x += v[i].x; acc.y += v[i].y; acc.z += v[i].z; acc.w += v[i].w;
                ++seglen;
            }
        }
        if (g + 16 < 128) {
#pragma unroll
            for (int i = 0; i < 8; ++i) {
                rowA[i] = sorted[pbeg + g + 16 + i];
                clsA[i] = clpos[pbeg + g + 16 + i];
            }
        }
        {
            float4 v[8];
#pragma unroll
            for (int i = 0; i < 8; ++i)
                v[i] = *reinterpret_cast<const float4*>(x + (size_t)rowB[i] * DD + lane * 4);
#pragma unroll
            for (int i = 0; i < 8; ++i) {
                if (clsB[i] != cur) flush(clsB[i]);
                acc.x += v[i].x; acc.y += v[i].y; acc.z += v[i].z; acc.w += v[i].w;
                ++seglen;
            }
        }
    }
    flush(0);
}

extern "C" void kernel_launch(void* const* d_in, const int* in_sizes, int n_in,
                              void* d_out, int out_size, void* d_ws, size_t ws_size,
                              hipStream_t stream) {
    const float* x    = (const float*)d_in[0];
    const float* cb   = (const float*)d_in[1];
    const float* bins = (const float*)d_in[2];
    const float* nums = (const float*)d_in[3];
    float* out = (float*)d_out;

    char* ws = (char*)d_ws;
    __bf16*         cbp    = (__bf16*)ws;                        // 512 KB permuted (dead after kmeans)
    float*          csq    = (float*)(ws + 512 * 1024);          // 4 KB
    unsigned short* bucket = (unsigned short*)(ws + 516 * 1024); // 256 KB
    int*            counts = (int*)(ws + 772 * 1024);            // 4 KB
    int*            offs   = (int*)(ws + 776 * 1024);            // 4 KB + 4
    int*            cursor = (int*)(ws + 781 * 1024);            // 4 KB
    unsigned short* clpos  = (unsigned short*)(ws + 785 * 1024); // 256 KB
    int*            sorted = (int*)cbp;                           // aliases cbp, 512 KB

    setup_kernel<<<1029, 256, 0, stream>>>(cb, bins, nums, out, counts, cbp, csq);
    kmeans_kernel<<<NPTS / 128, 256, 0, stream>>>(x, cbp, csq, bucket, counts, out);
    scan_kernel<<<1, 1024, 0, stream>>>(counts, offs, cursor);
    scatter_kernel<<<NPTS / 256, 256, 0, stream>>>(bucket, cursor, sorted, clpos);
    gather_kernel<<<NPTS / 512, 256, 0, stream>>>(x, sorted, clpos, out);
}